// Round 5
// baseline (189.566 us; speedup 1.0000x reference)
//
#include <hip/hip_runtime.h>

#define KCODES 512
#define DDIM   64
#define NPIX   1024                      // 32*32 spatial per batch
#define QELEMS (64 * DDIM * NPIX)        // 4194304

typedef float f32x2 __attribute__((ext_vector_type(2)));
typedef float f32x4 __attribute__((ext_vector_type(4)));

// Bit-exact emulation of the numpy fp32 reference (proven absmax=0 in R3/R4):
//   dot[nk] = seq-over-d sum of fl(x_d * w_dk)      (mul+add, NO fma)
//   dist    = fl( fl(x2 - fl(2*dot)) + w2 )         argmin = first minimum
// v_pk_mul_f32 / v_pk_add_f32 = two independent IEEE fp32 ops (bit-identical
// to scalar, proven R4). Feed from VGPRs ("v") — R4's "s" feed stalled on SMEM.
__global__ __launch_bounds__(256) void vq_kernel(
    const float* __restrict__ x, const float* __restrict__ w,
    float* __restrict__ qout, float* __restrict__ aout) {
#pragma clang fp contract(off)

  __shared__ float  w2f[KCODES];         // 2 KB fp32 ||w_k||^2 (np-ordered)
  __shared__ float  sm1[4][64];
  __shared__ int    si1[4][64];
  __shared__ int    skm[64];

  const int tid  = threadIdx.x;
  const int lane = tid & 63;
  const int wid  = __builtin_amdgcn_readfirstlane(tid >> 6);  // wave id, uniform
  const int b    = blockIdx.x >> 4;
  const int n0   = (blockIdx.x & 15) << 6;
  const size_t pixbase = (size_t)blockIdx.x << 6;

  // ---- w2 in fp32, sequential over d (numpy order), per block ----
#pragma unroll
  for (int kk = 0; kk < 2; ++kk) {
    int k = tid + kk * 256;
    float s = 0.0f;
    for (int d = 0; d < DDIM; ++d) {
      float v = w[d * KCODES + k];
      float p = v * v;                   // rounded product
      s = s + p;                         // rounded add, d ascending
    }
    w2f[k] = s;
  }

  // ---- x column into registers (coalesced; static indices only) ----
  float xr[DDIM];
  {
    const float* xp = x + (size_t)b * (DDIM * NPIX) + n0 + lane;
#pragma unroll
    for (int d = 0; d < DDIM; ++d) xr[d] = xp[(size_t)d * NPIX];
  }

  // ---- x2 per pixel, fp32 sequential over d (numpy order) ----
  float x2 = 0.0f;
#pragma unroll
  for (int d = 0; d < DDIM; ++d) {
    float p = xr[d] * xr[d];
    x2 = x2 + p;
  }
  __syncthreads();

  // ---- fp32 emulated path: wave `wid` owns k in [wid*128, wid*128+128) ----
  float m1 = 3.4e38f;
  int   i1 = 0;
  const int kbase = wid * 128;

#pragma unroll 1
  for (int kt = 0; kt < 8; ++kt) {
    const int k0 = kbase + kt * 16;
    f32x2 acc2[8];
#pragma unroll
    for (int j = 0; j < 8; ++j) acc2[j] = (f32x2){0.f, 0.f};

#pragma unroll
    for (int d = 0; d < DDIM; ++d) {
      // wave-uniform address -> VMEM dwordx4 broadcast loads (R3-proven path)
      const f32x4* wr = reinterpret_cast<const f32x4*>(w + d * KCODES + k0);
      f32x4 wa = wr[0];
      f32x4 wb = wr[1];
      f32x4 wc = wr[2];
      f32x4 wd = wr[3];
      f32x2 wp[8];
      wp[0] = __builtin_shufflevector(wa, wa, 0, 1);
      wp[1] = __builtin_shufflevector(wa, wa, 2, 3);
      wp[2] = __builtin_shufflevector(wb, wb, 0, 1);
      wp[3] = __builtin_shufflevector(wb, wb, 2, 3);
      wp[4] = __builtin_shufflevector(wc, wc, 0, 1);
      wp[5] = __builtin_shufflevector(wc, wc, 2, 3);
      wp[6] = __builtin_shufflevector(wd, wd, 0, 1);
      wp[7] = __builtin_shufflevector(wd, wd, 2, 3);
      float xv = xr[d];
      f32x2 xv2;
      xv2[0] = xv; xv2[1] = xv;
#pragma unroll
      for (int j = 0; j < 8; ++j) {
        f32x2 p;
        asm("v_pk_mul_f32 %0, %1, %2" : "=v"(p) : "v"(xv2), "v"(wp[j]));
        asm("v_pk_add_f32 %0, %0, %1" : "+v"(acc2[j]) : "v"(p));
      }
    }

#pragma unroll
    for (int j = 0; j < 16; ++j) {
      float a   = acc2[j >> 1][j & 1];
      float tdm = 2.0f * a;              // exact (*2)
      float t   = x2 - tdm;              // rounds at ulp(~64) — the decisive grid
      float s   = t + w2f[k0 + j];       // rounds
      bool lt = s < m1;                  // strict: first minimum wins (lowest k)
      m1 = lt ? s : m1;
      i1 = lt ? (k0 + j) : i1;
    }
  }

  sm1[wid][lane] = m1;
  si1[wid][lane] = i1;
  __syncthreads();

  // ---- merge 4 waves (ascending k ranges; strict < keeps lowest k on ties) ----
  if (tid < 64) {
    float M1 = sm1[0][lane];
    int   I1 = si1[0][lane];
#pragma unroll
    for (int c = 1; c < 4; ++c) {
      float c1 = sm1[c][lane];
      if (c1 < M1) { M1 = c1; I1 = si1[c][lane]; }
    }
    skm[lane] = I1;
    aout[pixbase + lane] = (float)I1;
  }
  __syncthreads();

  // ---- quantized write: 256 threads, each 16 d-rows, coalesced along n ----
  const int kmin = skm[lane];
  float* qp = qout + (size_t)b * (DDIM * NPIX) + n0 + lane;
#pragma unroll
  for (int dd = 0; dd < 16; ++dd) {
    int d = wid * 16 + dd;
    qp[(size_t)d * NPIX] = w[d * KCODES + kmin];
  }
}

extern "C" void kernel_launch(void* const* d_in, const int* in_sizes, int n_in,
                              void* d_out, int out_size, void* d_ws, size_t ws_size,
                              hipStream_t stream) {
  const float* x = (const float*)d_in[0];
  const float* w = (const float*)d_in[1];
  float* qout = (float*)d_out;
  float* aout = (float*)d_out + QELEMS;

  vq_kernel<<<64 * 16, 256, 0, stream>>>(x, w, qout, aout);
}

// Round 6
// 152.288 us; speedup vs baseline: 1.2448x; 1.2448x over previous
//
#include <hip/hip_runtime.h>

#define KCODES 512
#define DDIM   64
#define NPIX   1024                      // 32*32 spatial per batch
#define QELEMS (64 * DDIM * NPIX)        // 4194304

typedef float f32x2 __attribute__((ext_vector_type(2)));

// Bit-exact emulation of the numpy fp32 reference (proven absmax=0 R3/R4/R5):
//   dot[nk] = seq-over-d sum of fl(x_d * w_dk)      (mul+add, NO fma)
//   dist    = fl( fl(x2 - fl(2*dot)) + w2 )         argmin = first minimum
// Packed fp32 (v_pk_mul_f32/v_pk_add_f32) = two independent IEEE fp32 ops,
// bit-identical to scalar (proven R4/R5). Express as plain-C f32x2 ops so
// the COMPILER owns codegen/scheduling (R4 "s"-asm and R5 "v"-asm both
// defeated it: 39%/60% VALUBusy vs R3's 91%).
__global__ __launch_bounds__(256) void vq_kernel(
    const float* __restrict__ x, const float* __restrict__ w,
    float* __restrict__ qout, float* __restrict__ aout) {
#pragma clang fp contract(off)

  __shared__ float  w2f[KCODES];         // 2 KB fp32 ||w_k||^2 (np-ordered)
  __shared__ float  sm1[4][64];
  __shared__ int    si1[4][64];
  __shared__ int    skm[64];

  const int tid  = threadIdx.x;
  const int lane = tid & 63;
  const int wid  = __builtin_amdgcn_readfirstlane(tid >> 6);  // wave id, uniform
  const int b    = blockIdx.x >> 4;
  const int n0   = (blockIdx.x & 15) << 6;
  const size_t pixbase = (size_t)blockIdx.x << 6;

  // ---- w2 in fp32, sequential over d (numpy order), per block ----
#pragma unroll
  for (int kk = 0; kk < 2; ++kk) {
    int k = tid + kk * 256;
    float s = 0.0f;
    for (int d = 0; d < DDIM; ++d) {
      float v = w[d * KCODES + k];
      float p = v * v;                   // rounded product
      s = s + p;                         // rounded add, d ascending
    }
    w2f[k] = s;
  }

  // ---- x column into registers (coalesced; static indices only) ----
  float xr[DDIM];
  {
    const float* xp = x + (size_t)b * (DDIM * NPIX) + n0 + lane;
#pragma unroll
    for (int d = 0; d < DDIM; ++d) xr[d] = xp[(size_t)d * NPIX];
  }

  // ---- x2 per pixel, fp32 sequential over d (numpy order) ----
  float x2 = 0.0f;
#pragma unroll
  for (int d = 0; d < DDIM; ++d) {
    float p = xr[d] * xr[d];
    x2 = x2 + p;
  }
  __syncthreads();

  // ---- fp32 emulated path: wave `wid` owns k in [wid*128, wid*128+128) ----
  float m1 = 3.4e38f;
  int   i1 = 0;
  const int kbase = wid * 128;

#pragma unroll 1
  for (int kt = 0; kt < 8; ++kt) {
    const int k0 = kbase + kt * 16;
    f32x2 acc2[8];
#pragma unroll
    for (int j = 0; j < 8; ++j) acc2[j] = (f32x2){0.f, 0.f};

#pragma unroll
    for (int d = 0; d < DDIM; ++d) {
      // wave-uniform address -> scalar loads; compiler feeds v_pk_* directly
      const f32x2* wr2 = reinterpret_cast<const f32x2*>(w + d * KCODES + k0);
      float xv = xr[d];
      f32x2 xv2;
      xv2[0] = xv; xv2[1] = xv;
#pragma unroll
      for (int j = 0; j < 8; ++j) {
        f32x2 p = xv2 * wr2[j];          // v_pk_mul_f32 (rounded per lane)
        acc2[j] = acc2[j] + p;           // v_pk_add_f32 (rounded per lane)
      }
    }

#pragma unroll
    for (int j = 0; j < 16; ++j) {
      float a   = acc2[j >> 1][j & 1];
      float tdm = 2.0f * a;              // exact (*2)
      float t   = x2 - tdm;              // rounds at ulp(~64) — the decisive grid
      float s   = t + w2f[k0 + j];       // rounds
      bool lt = s < m1;                  // strict: first minimum wins (lowest k)
      m1 = lt ? s : m1;
      i1 = lt ? (k0 + j) : i1;
    }
  }

  sm1[wid][lane] = m1;
  si1[wid][lane] = i1;
  __syncthreads();

  // ---- merge 4 waves (ascending k ranges; strict < keeps lowest k on ties) ----
  if (tid < 64) {
    float M1 = sm1[0][lane];
    int   I1 = si1[0][lane];
#pragma unroll
    for (int c = 1; c < 4; ++c) {
      float c1 = sm1[c][lane];
      if (c1 < M1) { M1 = c1; I1 = si1[c][lane]; }
    }
    skm[lane] = I1;
    aout[pixbase + lane] = (float)I1;
  }
  __syncthreads();

  // ---- quantized write: 256 threads, each 16 d-rows, coalesced along n ----
  const int kmin = skm[lane];
  float* qp = qout + (size_t)b * (DDIM * NPIX) + n0 + lane;
#pragma unroll
  for (int dd = 0; dd < 16; ++dd) {
    int d = wid * 16 + dd;
    qp[(size_t)d * NPIX] = w[d * KCODES + kmin];
  }
}

extern "C" void kernel_launch(void* const* d_in, const int* in_sizes, int n_in,
                              void* d_out, int out_size, void* d_ws, size_t ws_size,
                              hipStream_t stream) {
  const float* x = (const float*)d_in[0];
  const float* w = (const float*)d_in[1];
  float* qout = (float*)d_out;
  float* aout = (float*)d_out + QELEMS;

  vq_kernel<<<64 * 16, 256, 0, stream>>>(x, w, qout, aout);
}